// Round 9
// baseline (158.867 us; speedup 1.0000x reference)
//
#include <hip/hip_runtime.h>

#define S_TOT 2048
#define BATCH 128
#define FEAT  256
#define CHUNK 64    // k-rows per pipeline stage
#define ROWH  68    // 64 halves + 4 pad; 136 B row stride
#define GROWS 16    // rows per gather block

typedef _Float16 f16x4 __attribute__((ext_vector_type(4)));
typedef _Float16 f16x2 __attribute__((ext_vector_type(2)));
typedef float f32x4 __attribute__((ext_vector_type(4)));

// Fused stats + Gram via MFMA, double-buffered, row-split 2 blocks/batch so
// all 256 CUs are used (R4 profile: 1 block/batch left half the chip idle).
// Correlation is affine-invariant: stage RAW f16 values, MFMA the Gram G,
// accumulate per-feature sum/sumsq of the SAME f16-rounded values in fp32,
// threshold (G - n*mi*mj) / ((n-1)*si*sj) > 0.999.
// Ref's +1e-6 std shift scales cov by ~2e-6: irrelevant vs 1e-3 margins.
// sigma=0 features: is_=0 -> cv=0 -> never selected (matches ref).
__global__ __launch_bounds__(1024) void k_cov(
        const float* __restrict__ x, const int* __restrict__ sep,
        int* __restrict__ colsum) {
    const int half = blockIdx.x;        // 0/1: which 128 Gram rows
    const int b = blockIdx.y;
    const int n = sep[0];
    const int t = threadIdx.x;
    const int l = t & 63;
    const int w = t >> 6;               // 0..15; wave tile = 32 rows x 64 cols
    const int wm = w >> 2, wn = w & 3;
    const int l15 = l & 15, lg = l >> 4;

    __shared__ _Float16 T[2][FEAT][ROWH];
    __shared__ float ms[FEAT], is_[FEAT];
    __shared__ int scount[FEAT];
    float* redf = (float*)&T[0][0][0];  // post-loop reuse: red[2][4][FEAT]

    // staging role: thread covers feature f, k-slots kg*16 .. kg*16+15
    const int f = t & 255;
    const int kg = t >> 8;              // 0..3

    f32x4 acc[2][4];
#pragma unroll
    for (int r = 0; r < 2; ++r)
#pragma unroll
        for (int c = 0; c < 4; ++c)
            acc[r][c] = (f32x4){0.f, 0.f, 0.f, 0.f};

    float psum = 0.f, psq = 0.f;
    float stage[16];

    const size_t xoff = (size_t)b * FEAT + f;
    const int NC = (n + CHUNK - 1) / CHUNK;

    if (t < FEAT) scount[t] = 0;

    // prologue: chunk 0 -> regs -> buf 0
    {
        const int k0 = kg * 16;
#pragma unroll
        for (int i = 0; i < 16; ++i) {
            const int s = k0 + i;
            stage[i] = (s < n) ? x[(size_t)s * (BATCH * FEAT) + xoff] : 0.f;
        }
#pragma unroll
        for (int i = 0; i < 16; i += 2) {
            _Float16 h0 = (_Float16)stage[i], h1 = (_Float16)stage[i + 1];
            float r0 = (float)h0, r1 = (float)h1;
            psum += r0 + r1;
            psq = fmaf(r0, r0, psq);
            psq = fmaf(r1, r1, psq);
            *(f16x2*)&T[0][f][k0 + i] = (f16x2){h0, h1};
        }
    }
    __syncthreads();

    for (int c = 0; c < NC; ++c) {
        const int cur = c & 1;
        const bool more = (c + 1 < NC);
        if (more) {
            const int k0 = (c + 1) * CHUNK + kg * 16;
#pragma unroll
            for (int i = 0; i < 16; ++i) {
                const int s = k0 + i;
                stage[i] = (s < n) ? x[(size_t)s * (BATCH * FEAT) + xoff] : 0.f;
            }
        }
        // MFMA on buf cur (prefetch loads drain under this)
#pragma unroll
        for (int ks = 0; ks < 4; ++ks) {
            const int kloc = ks * 16 + 4 * lg;
            f16x4 a[2], bb[4];
#pragma unroll
            for (int r = 0; r < 2; ++r)
                a[r] = *(const f16x4*)&T[cur][half * 128 + wm * 32 + r * 16 + l15][kloc];
#pragma unroll
            for (int c2 = 0; c2 < 4; ++c2)
                bb[c2] = *(const f16x4*)&T[cur][wn * 64 + c2 * 16 + l15][kloc];
#pragma unroll
            for (int r = 0; r < 2; ++r)
#pragma unroll
                for (int c2 = 0; c2 < 4; ++c2)
                    acc[r][c2] = __builtin_amdgcn_mfma_f32_16x16x16f16(
                        a[r], bb[c2], acc[r][c2], 0, 0, 0);
        }
        if (more) {
            const int nxt = cur ^ 1;
            const int kb = kg * 16;
#pragma unroll
            for (int i = 0; i < 16; i += 2) {
                _Float16 h0 = (_Float16)stage[i], h1 = (_Float16)stage[i + 1];
                float r0 = (float)h0, r1 = (float)h1;
                psum += r0 + r1;
                psq = fmaf(r0, r0, psq);
                psq = fmaf(r1, r1, psq);
                *(f16x2*)&T[nxt][f][kb + i] = (f16x2){h0, h1};
            }
            __syncthreads();
        }
    }

    // fold per-feature partials (4 kg-threads/feature); redf overlays T[0]
    __syncthreads();
    redf[kg * FEAT + f] = psum;
    redf[(4 + kg) * FEAT + f] = psq;
    __syncthreads();
    if (t < FEAT) {
        float s = redf[0 * FEAT + t] + redf[1 * FEAT + t] + redf[2 * FEAT + t] + redf[3 * FEAT + t];
        float q = redf[4 * FEAT + t] + redf[5 * FEAT + t] + redf[6 * FEAT + t] + redf[7 * FEAT + t];
        float m = s / (float)n;
        float var = (q - (float)n * m * m) / (float)(n - 1);
        ms[t] = m;
        is_[t] = (var > 0.f) ? rsqrtf(var) : 0.f;
    }
    __syncthreads();

    const float fn = (float)n;
    const float inv_nm1 = 1.f / (float)(n - 1);
#pragma unroll
    for (int c = 0; c < 4; ++c) {
        const int gj = wn * 64 + c * 16 + l15;
        const float mj = ms[gj], ij = is_[gj];
        int cnt = 0;
#pragma unroll
        for (int r = 0; r < 2; ++r) {
            const int gib = half * 128 + wm * 32 + r * 16 + 4 * lg;
#pragma unroll
            for (int q = 0; q < 4; ++q) {
                const int gi = gib + q;
                float cv = (acc[r][c][q] - fn * ms[gi] * mj) * inv_nm1 * is_[gi] * ij;
                if (gi <= gj && cv > 0.999f) cnt++;
            }
        }
        if (cnt) atomicAdd(&scount[gj], cnt);
    }
    __syncthreads();
    if (t < FEAT && scount[t]) atomicAdd(&colsum[b * FEAT + t], scount[t]);
}

// stable order (selected features first) + counts, ballot prefix.
__global__ void k_select(const int* __restrict__ colsum, int* __restrict__ order,
                         int* __restrict__ counts) {
    __shared__ int wsum[4];
    const int b = blockIdx.x;
    const int j = threadIdx.x;         // 0..255
    const int sel = (colsum[b * FEAT + j] == 1) ? 1 : 0;
    unsigned long long mask = __ballot(sel);
    const int lane = j & 63;
    const int wid = j >> 6;
    int pre = __popcll(mask & ((1ull << lane) - 1ull));
    if (lane == 0) wsum[wid] = __popcll(mask);
    __syncthreads();
    int woff = 0;
#pragma unroll
    for (int w = 0; w < 4; ++w) woff += (w < wid) ? wsum[w] : 0;
    const int total = wsum[0] + wsum[1] + wsum[2] + wsum[3];
    if (sel) {
        order[b * FEAT + woff + pre] = j;
    } else {
        int unsel_pre = j - (woff + pre);
        order[b * FEAT + total + unsel_pre] = j;
    }
    if (j == 0) counts[b] = total;
}

// gather through LDS: stage GROWS rows coalesced (float4), permute in LDS,
// store contiguous float4 (4 cols/thread).
__global__ __launch_bounds__(256) void k_gather(
        const float* __restrict__ x, const int* __restrict__ order,
        const int* __restrict__ counts, float* __restrict__ out) {
    const int b = blockIdx.y;
    const int s0 = blockIdx.x * GROWS;
    const int t = threadIdx.x;

    __shared__ float T[GROWS][FEAT];
    __shared__ int ord_s[FEAT];
    __shared__ int cnt_s;

    ord_s[t] = order[b * FEAT + t];
    if (t == 0) cnt_s = counts[b];

    const size_t bbase = (size_t)b * FEAT;
#pragma unroll
    for (int i = 0; i < (GROWS * FEAT) / (256 * 4); ++i) {  // 4 float4/thread
        const int idx = i * 256 + t;
        const int row = idx >> 6;
        const int f4 = (idx & 63) * 4;
        float4 v = *(const float4*)&x[(size_t)(s0 + row) * (BATCH * FEAT) + bbase + f4];
        *(float4*)&T[row][f4] = v;
    }
    __syncthreads();

    const int c4 = (t & 63) * 4;
    const int tr = t >> 6;               // 0..3
    const int cnt = cnt_s;
    const int o0 = ord_s[c4 + 0], o1 = ord_s[c4 + 1];
    const int o2 = ord_s[c4 + 2], o3 = ord_s[c4 + 3];
#pragma unroll
    for (int r = tr; r < GROWS; r += 4) {
        float4 v;
        v.x = (c4 + 0 < cnt) ? T[r][o0] : 0.f;
        v.y = (c4 + 1 < cnt) ? T[r][o1] : 0.f;
        v.z = (c4 + 2 < cnt) ? T[r][o2] : 0.f;
        v.w = (c4 + 3 < cnt) ? T[r][o3] : 0.f;
        *(float4*)&out[(size_t)(s0 + r) * (BATCH * FEAT) + bbase + c4] = v;
    }
}

extern "C" void kernel_launch(void* const* d_in, const int* in_sizes, int n_in,
                              void* d_out, int out_size, void* d_ws, size_t ws_size,
                              hipStream_t stream) {
    const float* x = (const float*)d_in[0];
    const int* sep = (const int*)d_in[1];
    float* out = (float*)d_out;

    int* colsum = (int*)d_ws;
    int* order = colsum + BATCH * FEAT;
    int* counts = order + BATCH * FEAT;

    hipMemsetAsync(colsum, 0, BATCH * FEAT * sizeof(int), stream);

    k_cov<<<dim3(2, BATCH), dim3(1024), 0, stream>>>(x, sep, colsum);

    k_select<<<dim3(BATCH), dim3(FEAT), 0, stream>>>(colsum, order, counts);

    k_gather<<<dim3(S_TOT / GROWS, BATCH), dim3(256), 0, stream>>>(x, order, counts, out);
}

// Round 11
// 128.709 us; speedup vs baseline: 1.2343x; 1.2343x over previous
//
#include <hip/hip_runtime.h>

#define S_TOT 2048
#define BATCH 128
#define FEAT  256
#define CHUNK 64    // k-rows per pipeline stage
#define ROWH  68    // 64 halves + 4 pad; 136 B row stride
#define GROWS 16    // rows per gather block

typedef _Float16 f16x4 __attribute__((ext_vector_type(4)));
typedef _Float16 f16x2 __attribute__((ext_vector_type(2)));
typedef float f32x4 __attribute__((ext_vector_type(4)));

// Fused stats + Gram via MFMA, double-buffered, row-split 2 blocks/batch.
// XCD-pair swizzle: both halves of batch b land on the SAME XCD (8 dispatch
// slots apart) so the duplicate read of b's x-slice is served by that XCD's
// L2 instead of HBM (R9 analysis: cov was HBM-bound on the 2x duplicate
// read, 2.66us/iter floor -> ~1.35 with dedup).
// Correlation is affine-invariant: stage RAW f16 values, MFMA the Gram G,
// accumulate per-feature sum/sumsq of the SAME f16-rounded values in fp32,
// threshold (G - n*mi*mj) / ((n-1)*si*sj) > 0.999.
// Ref's +1e-6 std shift scales cov by ~2e-6: irrelevant vs 1e-3 margins.
// sigma=0 features: is_=0 -> cv=0 -> never selected (matches ref).
// Partial counts go to colsum_part[half] via plain stores (no memset needed).
__global__ __launch_bounds__(1024) void k_cov(
        const float* __restrict__ x, const int* __restrict__ sep,
        int* __restrict__ colsum_part) {
    const int d = blockIdx.x;               // 0..255
    const int b = (d & 7) + 8 * (d >> 4);   // XCD-pair remap (bijective)
    const int half = (d >> 3) & 1;          // halves of b are 8 slots apart
    const int n = sep[0];
    const int t = threadIdx.x;
    const int l = t & 63;
    const int w = t >> 6;               // 0..15; wave tile = 32 rows x 64 cols
    const int wm = w >> 2, wn = w & 3;
    const int l15 = l & 15, lg = l >> 4;

    __shared__ _Float16 T[2][FEAT][ROWH];
    __shared__ float ms[FEAT], is_[FEAT];
    __shared__ int scount[FEAT];
    float* redf = (float*)&T[0][0][0];  // post-loop reuse: red[2][4][FEAT]

    // staging role: thread covers feature f, k-slots kg*16 .. kg*16+15
    const int f = t & 255;
    const int kg = t >> 8;              // 0..3

    f32x4 acc[2][4];
#pragma unroll
    for (int r = 0; r < 2; ++r)
#pragma unroll
        for (int c = 0; c < 4; ++c)
            acc[r][c] = (f32x4){0.f, 0.f, 0.f, 0.f};

    float psum = 0.f, psq = 0.f;
    float stage[16];

    const size_t xoff = (size_t)b * FEAT + f;
    const int NC = (n + CHUNK - 1) / CHUNK;

    if (t < FEAT) scount[t] = 0;

    // prologue: chunk 0 -> regs -> buf 0
    {
        const int k0 = kg * 16;
#pragma unroll
        for (int i = 0; i < 16; ++i) {
            const int s = k0 + i;
            stage[i] = (s < n) ? x[(size_t)s * (BATCH * FEAT) + xoff] : 0.f;
        }
#pragma unroll
        for (int i = 0; i < 16; i += 2) {
            _Float16 h0 = (_Float16)stage[i], h1 = (_Float16)stage[i + 1];
            float r0 = (float)h0, r1 = (float)h1;
            psum += r0 + r1;
            psq = fmaf(r0, r0, psq);
            psq = fmaf(r1, r1, psq);
            *(f16x2*)&T[0][f][k0 + i] = (f16x2){h0, h1};
        }
    }
    __syncthreads();

    for (int c = 0; c < NC; ++c) {
        const int cur = c & 1;
        const bool more = (c + 1 < NC);
        if (more) {
            const int k0 = (c + 1) * CHUNK + kg * 16;
#pragma unroll
            for (int i = 0; i < 16; ++i) {
                const int s = k0 + i;
                stage[i] = (s < n) ? x[(size_t)s * (BATCH * FEAT) + xoff] : 0.f;
            }
        }
        // MFMA on buf cur (prefetch loads drain under this)
#pragma unroll
        for (int ks = 0; ks < 4; ++ks) {
            const int kloc = ks * 16 + 4 * lg;
            f16x4 a[2], bb[4];
#pragma unroll
            for (int r = 0; r < 2; ++r)
                a[r] = *(const f16x4*)&T[cur][half * 128 + wm * 32 + r * 16 + l15][kloc];
#pragma unroll
            for (int c2 = 0; c2 < 4; ++c2)
                bb[c2] = *(const f16x4*)&T[cur][wn * 64 + c2 * 16 + l15][kloc];
#pragma unroll
            for (int r = 0; r < 2; ++r)
#pragma unroll
                for (int c2 = 0; c2 < 4; ++c2)
                    acc[r][c2] = __builtin_amdgcn_mfma_f32_16x16x16f16(
                        a[r], bb[c2], acc[r][c2], 0, 0, 0);
        }
        if (more) {
            const int nxt = cur ^ 1;
            const int kb = kg * 16;
#pragma unroll
            for (int i = 0; i < 16; i += 2) {
                _Float16 h0 = (_Float16)stage[i], h1 = (_Float16)stage[i + 1];
                float r0 = (float)h0, r1 = (float)h1;
                psum += r0 + r1;
                psq = fmaf(r0, r0, psq);
                psq = fmaf(r1, r1, psq);
                *(f16x2*)&T[nxt][f][kb + i] = (f16x2){h0, h1};
            }
        }
        __syncthreads();
    }

    // fold per-feature partials (4 kg-threads/feature); redf overlays T[0]
    redf[kg * FEAT + f] = psum;
    redf[(4 + kg) * FEAT + f] = psq;
    __syncthreads();
    if (t < FEAT) {
        float s = redf[0 * FEAT + t] + redf[1 * FEAT + t] + redf[2 * FEAT + t] + redf[3 * FEAT + t];
        float q = redf[4 * FEAT + t] + redf[5 * FEAT + t] + redf[6 * FEAT + t] + redf[7 * FEAT + t];
        float m = s / (float)n;
        float var = (q - (float)n * m * m) / (float)(n - 1);
        ms[t] = m;
        is_[t] = (var > 0.f) ? rsqrtf(var) : 0.f;
    }
    __syncthreads();

    const float fn = (float)n;
    const float inv_nm1 = 1.f / (float)(n - 1);
#pragma unroll
    for (int c = 0; c < 4; ++c) {
        const int gj = wn * 64 + c * 16 + l15;
        const float mj = ms[gj], ij = is_[gj];
        int cnt = 0;
#pragma unroll
        for (int r = 0; r < 2; ++r) {
            const int gib = half * 128 + wm * 32 + r * 16 + 4 * lg;
#pragma unroll
            for (int q = 0; q < 4; ++q) {
                const int gi = gib + q;
                float cv = (acc[r][c][q] - fn * ms[gi] * mj) * inv_nm1 * is_[gi] * ij;
                if (gi <= gj && cv > 0.999f) cnt++;
            }
        }
        if (cnt) atomicAdd(&scount[gj], cnt);
    }
    __syncthreads();
    if (t < FEAT) colsum_part[(half * BATCH + b) * FEAT + t] = scount[t];
}

// stable order (selected features first) + counts, ballot prefix.
// Sums the two per-half partial counts (no memset / atomics needed).
__global__ void k_select(const int* __restrict__ colsum_part, int* __restrict__ order,
                         int* __restrict__ counts) {
    __shared__ int wsum[4];
    const int b = blockIdx.x;
    const int j = threadIdx.x;         // 0..255
    const int cs = colsum_part[b * FEAT + j] +
                   colsum_part[(BATCH + b) * FEAT + j];
    const int sel = (cs == 1) ? 1 : 0;
    unsigned long long mask = __ballot(sel);
    const int lane = j & 63;
    const int wid = j >> 6;
    int pre = __popcll(mask & ((1ull << lane) - 1ull));
    if (lane == 0) wsum[wid] = __popcll(mask);
    __syncthreads();
    int woff = 0;
#pragma unroll
    for (int w = 0; w < 4; ++w) woff += (w < wid) ? wsum[w] : 0;
    const int total = wsum[0] + wsum[1] + wsum[2] + wsum[3];
    if (sel) {
        order[b * FEAT + woff + pre] = j;
    } else {
        int unsel_pre = j - (woff + pre);
        order[b * FEAT + total + unsel_pre] = j;
    }
    if (j == 0) counts[b] = total;
}

// gather through LDS: stage GROWS rows coalesced (float4), permute in LDS,
// store contiguous float4 (4 cols/thread), nontemporal (out never re-read).
__global__ __launch_bounds__(256) void k_gather(
        const float* __restrict__ x, const int* __restrict__ order,
        const int* __restrict__ counts, float* __restrict__ out) {
    const int b = blockIdx.y;
    const int s0 = blockIdx.x * GROWS;
    const int t = threadIdx.x;

    __shared__ float T[GROWS][FEAT];
    __shared__ int ord_s[FEAT];
    __shared__ int cnt_s;

    ord_s[t] = order[b * FEAT + t];
    if (t == 0) cnt_s = counts[b];

    const size_t bbase = (size_t)b * FEAT;
#pragma unroll
    for (int i = 0; i < (GROWS * FEAT) / (256 * 4); ++i) {  // 4 float4/thread
        const int idx = i * 256 + t;
        const int row = idx >> 6;
        const int f4 = (idx & 63) * 4;
        float4 v = *(const float4*)&x[(size_t)(s0 + row) * (BATCH * FEAT) + bbase + f4];
        *(float4*)&T[row][f4] = v;
    }
    __syncthreads();

    const int c4 = (t & 63) * 4;
    const int tr = t >> 6;               // 0..3
    const int cnt = cnt_s;
    const int o0 = ord_s[c4 + 0], o1 = ord_s[c4 + 1];
    const int o2 = ord_s[c4 + 2], o3 = ord_s[c4 + 3];
#pragma unroll
    for (int r = tr; r < GROWS; r += 4) {
        f32x4 v;
        v.x = (c4 + 0 < cnt) ? T[r][o0] : 0.f;
        v.y = (c4 + 1 < cnt) ? T[r][o1] : 0.f;
        v.z = (c4 + 2 < cnt) ? T[r][o2] : 0.f;
        v.w = (c4 + 3 < cnt) ? T[r][o3] : 0.f;
        __builtin_nontemporal_store(v,
            (f32x4*)&out[(size_t)(s0 + r) * (BATCH * FEAT) + bbase + c4]);
    }
}

extern "C" void kernel_launch(void* const* d_in, const int* in_sizes, int n_in,
                              void* d_out, int out_size, void* d_ws, size_t ws_size,
                              hipStream_t stream) {
    const float* x = (const float*)d_in[0];
    const int* sep = (const int*)d_in[1];
    float* out = (float*)d_out;

    int* colsum_part = (int*)d_ws;                     // [2][BATCH][FEAT]
    int* order = colsum_part + 2 * BATCH * FEAT;
    int* counts = order + BATCH * FEAT;

    k_cov<<<dim3(2 * BATCH), dim3(1024), 0, stream>>>(x, sep, colsum_part);

    k_select<<<dim3(BATCH), dim3(FEAT), 0, stream>>>(colsum_part, order, counts);

    k_gather<<<dim3(S_TOT / GROWS, BATCH), dim3(256), 0, stream>>>(x, order, counts, out);
}